// Round 1
// 656.260 us; speedup vs baseline: 1.0526x; 1.0526x over previous
//
#include <hip/hip_runtime.h>

#define NB 512
#define NC 32
#define NT 8192
#define TP 1024        // NT / 8 pooled windows
#define NG 11
#define TILE 64        // time-windows per block (512 floats of t per channel)
#define NSLICE 4       // channel slices (one per wave)
#define QPB (TILE * 2) // 128 quad-sums (4 floats each) per channel-tile

typedef float f32x4 __attribute__((ext_vector_type(4)));
typedef float f32x2 __attribute__((ext_vector_type(2)));

__global__ __launch_bounds__(256, 4) void local_gnn_kernel(
    const float* __restrict__ xg,
    const float* __restrict__ W,
    const float* __restrict__ bias,
    float* __restrict__ out)
{
    // red[g][y][q]: quad q (0..127) = 4-sample relu partial sum; 22528 B
    __shared__ float red[NG][NSLICE][QPB];

    const int xw = threadIdx.x & 63;          // lane
    const int y  = threadIdx.x >> 6;          // channel slice — wave-uniform
    const int bb = blockIdx.x >> 4;           // batch (TP/TILE = 16 tiles)
    const int tb = blockIdx.x & 15;           // tile index

    // lane i covers quad i (first 1 KB) and quad 64+i (second 1 KB):
    // fully contiguous 16 B/lane -> each 64B line touched by exactly one instr.
    const float* xb = xg + (size_t)bb * (NC * NT) + tb * (TILE * 8) + 4 * xw;
    const float* Wb = W + tb * (TILE * 8) + 4 * xw;

    float accA[NG], accB[NG];
    #pragma unroll
    for (int g = 0; g < NG; ++g) { accA[g] = 0.0f; accB[g] = 0.0f; }

#define DO_CH(c, g) do {                                                      \
    f32x4 xa = __builtin_nontemporal_load((const f32x4*)(xb + (c) * NT));      \
    f32x4 xc = __builtin_nontemporal_load((const f32x4*)(xb + (c) * NT + 256));\
    f32x4 wa = *(const f32x4*)(Wb + (c) * NT);                                 \
    f32x4 wc = *(const f32x4*)(Wb + (c) * NT + 256);                           \
    const float nbc = -bias[c];                                                \
    float sA, sB;                                                              \
    sA  = fmaxf(fmaf(xa.x, wa.x, nbc), 0.0f);                                  \
    sA += fmaxf(fmaf(xa.y, wa.y, nbc), 0.0f);                                  \
    sA += fmaxf(fmaf(xa.z, wa.z, nbc), 0.0f);                                  \
    sA += fmaxf(fmaf(xa.w, wa.w, nbc), 0.0f);                                  \
    sB  = fmaxf(fmaf(xc.x, wc.x, nbc), 0.0f);                                  \
    sB += fmaxf(fmaf(xc.y, wc.y, nbc), 0.0f);                                  \
    sB += fmaxf(fmaf(xc.z, wc.z, nbc), 0.0f);                                  \
    sB += fmaxf(fmaf(xc.w, wc.w, nbc), 0.0f);                                  \
    accA[g] += sA; accB[g] += sB;                                              \
} while (0)

    // wave-uniform switch: lanes 0..63 -> y=0, etc. No divergence.
    switch (y) {
    case 0:
        DO_CH(0, 0); DO_CH(1, 0); DO_CH(2, 1); DO_CH(3, 1);
        DO_CH(4, 2); DO_CH(5, 2); DO_CH(6, 6); DO_CH(8, 7);
        break;
    case 1:
        DO_CH(9, 7);  DO_CH(10, 8); DO_CH(11, 8); DO_CH(12, 9);
        DO_CH(13, 10); DO_CH(14, 10); DO_CH(15, 8);
        break;
    case 2:
        DO_CH(16, 3); DO_CH(17, 3); DO_CH(19, 4); DO_CH(20, 4);
        DO_CH(21, 5); DO_CH(22, 5); DO_CH(23, 6);
        break;
    default:
        DO_CH(24, 6); DO_CH(26, 8); DO_CH(27, 7); DO_CH(28, 8);
        DO_CH(29, 8); DO_CH(30, 9); DO_CH(31, 10);
        break;
    }
#undef DO_CH

    // store quad partials: 64 lanes x 4 B contiguous per store -> conflict-free
    #pragma unroll
    for (int g = 0; g < NG; ++g) {
        red[g][y][xw]      = accA[g];
        red[g][y][64 + xw] = accB[g];
    }

    __syncthreads();

    // group sizes {2,2,2,2,2,2,3,3,6,2,3}; divisor = 8 * size
    constexpr float INV[NG] = {1.f/16, 1.f/16, 1.f/16, 1.f/16, 1.f/16, 1.f/16,
                               1.f/24, 1.f/24, 1.f/48, 1.f/16, 1.f/24};

    float* ob = out + (size_t)bb * (NG * TP) + tb * TILE;
    #pragma unroll
    for (int base = 0; base < NG * TILE; base += 256) {
        const int idx = base + (int)threadIdx.x;
        if (idx < NG * TILE) {
            const int g = idx >> 6;         // wave-uniform per iteration
            const int w = idx & 63;         // window -> quads 2w, 2w+1
            // ds_read_b64 per slice: lane stride 8 B, 2-way bank alias (free)
            const f32x2 a0 = *(const f32x2*)&red[g][0][2 * w];
            const f32x2 a1 = *(const f32x2*)&red[g][1][2 * w];
            const f32x2 a2 = *(const f32x2*)&red[g][2][2 * w];
            const f32x2 a3 = *(const f32x2*)&red[g][3][2 * w];
            const float s = (a0.x + a0.y) + (a1.x + a1.y) +
                            (a2.x + a2.y) + (a3.x + a3.y);
            __builtin_nontemporal_store(s * INV[g], ob + (size_t)g * TP + w);
        }
    }
}

extern "C" void kernel_launch(void* const* d_in, const int* in_sizes, int n_in,
                              void* d_out, int out_size, void* d_ws, size_t ws_size,
                              hipStream_t stream) {
    const float* x    = (const float*)d_in[0];
    const float* W    = (const float*)d_in[1];
    const float* bias = (const float*)d_in[2];
    float* out        = (float*)d_out;

    const int grid = NB * (TP / TILE);   // 512 * 16 = 8192 blocks
    hipLaunchKernelGGL(local_gnn_kernel, dim3(grid), dim3(256), 0, stream,
                       x, W, bias, out);
}